// Round 2
// baseline (137.276 us; speedup 1.0000x reference)
//
#include <hip/hip_runtime.h>
#include <hip/hip_bf16.h>
#include <stdint.h>

#define HW 192
#define NC 128
#define KEPS 1e-5f

typedef __attribute__((ext_vector_type(8))) short short8;
typedef __attribute__((ext_vector_type(4))) float f32x4;

// ---------------------------------------------------------------------------
// Prep: f32 [n][C][HW] -> bf16 [n][HW][C], linear (no swizzle; no LDS consumer)
// ---------------------------------------------------------------------------
__global__ void prep_kernel(const float* __restrict__ prob,
                            const float* __restrict__ gal,
                            unsigned short* __restrict__ probT,
                            unsigned short* __restrict__ galT) {
  int b = blockIdx.x;            // 512 blocks: 128 slices x 4 quarters
  int slice = b >> 2;
  int part = b & 3;
  const float* src;
  unsigned short* dst;
  if (slice < 64) { src = prob + (size_t)slice * NC * HW; dst = probT + (size_t)slice * HW * NC; }
  else            { src = gal + (size_t)(slice - 64) * NC * HW; dst = galT + (size_t)(slice - 64) * HW * NC; }
  int begin = part * (NC * HW / 4);
  int end = begin + (NC * HW / 4);
  for (int idx = begin + threadIdx.x; idx < end; idx += blockDim.x) {
    int hw = idx >> 7;           // 0..191
    int c = idx & 127;
    dst[hw * NC + c] =
        __builtin_bit_cast(unsigned short, __float2bfloat16(src[c * HW + hw]));
  }
}

// ---------------------------------------------------------------------------
// Pair kernel: 512 blocks = (g, probe-chunk-of-8); bid = g*8 + pc so XCD=pc.
// 4 waves; wave w owns gallery rows w*48..w*48+47 (frags persist in regs),
// all 192 probe cols. Probe frags read straight from L2 (no LDS staging).
// ---------------------------------------------------------------------------
__global__ __launch_bounds__(256, 2)
void pair_kernel(const unsigned short* __restrict__ galT,
                 const unsigned short* __restrict__ probT,
                 const float* __restrict__ fc_w,
                 float* __restrict__ Wout,
                 float* __restrict__ sPart,
                 float* __restrict__ qPart) {
  __shared__ float cmPart[4][HW];   // per-wave col-max partials
  __shared__ float red[8];

  const int tid = threadIdx.x;
  const int lane = tid & 63;
  const int wid = tid >> 6;          // 0..3 : gallery row group
  const int q = lane >> 4;           // 0..3
  const int r16 = lane & 15;

  const int g = blockIdx.x >> 3;
  const int pc = blockIdx.x & 7;     // 8 probes per block

  // fc weights: col-max feats j=s (tid<192); row-max feats j=192+r
  const float wcm = (tid < HW) ? fc_w[tid] : 0.f;
  float wrm[3];
  #pragma unroll
  for (int m = 0; m < 3; ++m)
    wrm[m] = (r16 < 4) ? fc_w[HW + wid * 48 + m * 16 + q * 4 + r16] : 0.f;

  // persistent gallery A-fragments: a[m][ks], row = wid*48+m*16+r16, k-chunk ks*64+q*16 B
  const char* gbase = (const char*)(galT + (size_t)g * HW * NC);
  short8 a[3][4];
  #pragma unroll
  for (int m = 0; m < 3; ++m)
    #pragma unroll
    for (int ks = 0; ks < 4; ++ks)
      a[m][ks] = *(const short8*)(gbase + (wid * 48 + m * 16 + r16) * 256 + ks * 64 + q * 16);

  float s_acc = 0.f, q_acc = 0.f;

  for (int i = 0; i < 8; ++i) {
    const int p = pc * 8 + i;
    const char* pbase = (const char*)(probT + (size_t)p * HW * NC) + r16 * 256 + q * 16;

    f32x4 acc[3][12];
    #pragma unroll
    for (int m = 0; m < 3; ++m)
      #pragma unroll
      for (int n = 0; n < 12; ++n) acc[m][n] = (f32x4){0.f, 0.f, 0.f, 0.f};

    #pragma unroll
    for (int n = 0; n < 12; ++n) {
      #pragma unroll
      for (int ks = 0; ks < 4; ++ks) {
        short8 bf = *(const short8*)(pbase + n * 4096 + ks * 64);
        #pragma unroll
        for (int m = 0; m < 3; ++m)
          acc[m][n] = __builtin_amdgcn_mfma_f32_16x16x32_bf16(a[m][ks], bf, acc[m][n], 0, 0, 0);
      }
    }

    // ---- row-max (max over all 192 s) : wave-local complete ----
    float wn = 0.f;
    #pragma unroll
    for (int m = 0; m < 3; ++m) {
      #pragma unroll
      for (int j = 0; j < 4; ++j) {
        float rm = acc[m][0][j];
        #pragma unroll
        for (int n = 1; n < 12; ++n) rm = fmaxf(rm, acc[m][n][j]);
        rm = fmaxf(rm, __shfl_xor(rm, 1));
        rm = fmaxf(rm, __shfl_xor(rm, 2));
        rm = fmaxf(rm, __shfl_xor(rm, 4));
        rm = fmaxf(rm, __shfl_xor(rm, 8));
        if (r16 == j) {                 // lane (q, r16=j) owns row m*16+q*4+j
          s_acc += rm; q_acc += rm * rm; wn += rm * wrm[m];
        }
      }
    }
    // ---- col-max partial over this wave's 48 rows ----
    #pragma unroll
    for (int n = 0; n < 12; ++n) {
      float cm = fmaxf(fmaxf(acc[0][n][0], acc[0][n][1]),
                       fmaxf(acc[0][n][2], acc[0][n][3]));
      #pragma unroll
      for (int m = 1; m < 3; ++m)
        #pragma unroll
        for (int j = 0; j < 4; ++j) cm = fmaxf(cm, acc[m][n][j]);
      cm = fmaxf(cm, __shfl_xor(cm, 16));
      cm = fmaxf(cm, __shfl_xor(cm, 32));
      if (lane < 16) cmPart[wid][n * 16 + r16] = cm;
    }
    // wave-reduce row-max dot partial
    #pragma unroll
    for (int msk = 1; msk < 64; msk <<= 1) wn += __shfl_xor(wn, msk);
    if (lane == 0) red[wid] = wn;
    __syncthreads();

    // ---- combine col-max across waves; finish stats + W ----
    float wc2 = 0.f;
    if (tid < HW) {
      float cm = fmaxf(fmaxf(cmPart[0][tid], cmPart[1][tid]),
                       fmaxf(cmPart[2][tid], cmPart[3][tid]));
      s_acc += cm; q_acc += cm * cm; wc2 = cm * wcm;
    }
    #pragma unroll
    for (int msk = 1; msk < 64; msk <<= 1) wc2 += __shfl_xor(wc2, msk);
    if (lane == 0) red[4 + wid] = wc2;
    float rmSum = (tid == 0) ? (red[0] + red[1] + red[2] + red[3]) : 0.f;
    __syncthreads();
    if (tid == 0) Wout[p * 64 + g] = rmSum + red[4] + red[5] + red[6] + red[7];
  }

  __syncthreads();   // protect red[] before stats writes
  #pragma unroll
  for (int msk = 1; msk < 64; msk <<= 1) {
    s_acc += __shfl_xor(s_acc, msk);
    q_acc += __shfl_xor(q_acc, msk);
  }
  if (lane == 0) { red[wid] = s_acc; red[4 + wid] = q_acc; }
  __syncthreads();
  if (tid == 0) {
    sPart[blockIdx.x] = red[0] + red[1] + red[2] + red[3];
    qPart[blockIdx.x] = red[4] + red[5] + red[6] + red[7];
  }
}

// ---------------------------------------------------------------------------
// Finalize: exact BN -> fc -> BN chain. One block, 512 threads.
// ---------------------------------------------------------------------------
__device__ __forceinline__ float block_sum_512(float v, float* rbuf, float* bc) {
  int t = threadIdx.x, lane = t & 63, wid = t >> 6;
  #pragma unroll
  for (int m = 1; m < 64; m <<= 1) v += __shfl_xor(v, m);
  if (lane == 0) rbuf[wid] = v;
  __syncthreads();
  if (t == 0) {
    float r = 0.f;
    for (int i = 0; i < 8; ++i) r += rbuf[i];
    bc[0] = r;
  }
  __syncthreads();
  float res = bc[0];
  __syncthreads();
  return res;
}

__global__ void finalize_kernel(const float* __restrict__ Wv,
                                const float* __restrict__ sPart,
                                const float* __restrict__ qPart,
                                const float* __restrict__ fc_w,
                                const float* __restrict__ fc_b,
                                const float* __restrict__ bn_g,
                                const float* __restrict__ bn_b,
                                const float* __restrict__ lbn_g,
                                const float* __restrict__ lbn_b,
                                float* __restrict__ out) {
  __shared__ float rbuf[8];
  __shared__ float bc[1];
  const int t = threadIdx.x;  // 512

  float s_l = sPart[t];
  float q_l = qPart[t];
  float w_l = (t < 384) ? fc_w[t] : 0.f;
  float S = block_sum_512(s_l, rbuf, bc);
  float Q = block_sum_512(q_l, rbuf, bc);
  float SW = block_sum_512(w_l, rbuf, bc);

  const float Nf = 4096.0f * 384.0f;
  float mu = S / Nf;
  float var = Q / Nf - mu * mu;
  float istd = rsqrtf(var + KEPS);
  float cA = istd * bn_g[0];
  float off = bn_b[0] * SW + fc_b[0] - cA * mu * SW;

  float l[8];
  float ls = 0.f;
  #pragma unroll
  for (int i = 0; i < 8; ++i) {
    int n = t + i * 512;
    l[i] = cA * Wv[n] + off;
    ls += l[i];
  }
  float LS = block_sum_512(ls, rbuf, bc);
  float lmu = LS / 4096.0f;
  float lq = 0.f;
  #pragma unroll
  for (int i = 0; i < 8; ++i) { float d = l[i] - lmu; lq += d * d; }
  float LQ = block_sum_512(lq, rbuf, bc);
  float lvar = LQ / 4096.0f;
  float sc = lbn_g[0] * rsqrtf(lvar + KEPS);
  float lb = lbn_b[0];
  #pragma unroll
  for (int i = 0; i < 8; ++i) {
    int n = t + i * 512;
    out[n] = (l[i] - lmu) * sc + lb;
  }
}

// ---------------------------------------------------------------------------
extern "C" void kernel_launch(void* const* d_in, const int* in_sizes, int n_in,
                              void* d_out, int out_size, void* d_ws, size_t ws_size,
                              hipStream_t stream) {
  const float* prob  = (const float*)d_in[0];
  const float* gal   = (const float*)d_in[1];
  const float* bn_g  = (const float*)d_in[2];
  const float* bn_b  = (const float*)d_in[3];
  const float* fc_w  = (const float*)d_in[4];
  const float* fc_b  = (const float*)d_in[5];
  const float* lbn_g = (const float*)d_in[6];
  const float* lbn_b = (const float*)d_in[7];
  float* out = (float*)d_out;

  char* ws = (char*)d_ws;
  unsigned short* probT = (unsigned short*)(ws);            // 3,145,728 B
  unsigned short* galT  = (unsigned short*)(ws + 3145728);  // 3,145,728 B
  float* Wv    = (float*)(ws + 6291456);                    // 16384 B
  float* sPart = (float*)(ws + 6307840);                    // 2048 B
  float* qPart = (float*)(ws + 6309888);                    // 2048 B

  prep_kernel<<<512, 256, 0, stream>>>(prob, gal, probT, galT);
  pair_kernel<<<512, 256, 0, stream>>>(galT, probT, fc_w, Wv, sPart, qPart);
  finalize_kernel<<<1, 512, 0, stream>>>(Wv, sPart, qPart, fc_w, fc_b,
                                         bn_g, bn_b, lbn_g, lbn_b, out);
}

// Round 3
// 80.193 us; speedup vs baseline: 1.7118x; 1.7118x over previous
//
#include <hip/hip_runtime.h>
#include <hip/hip_bf16.h>
#include <stdint.h>

#define HW 192
#define NC 128
#define KEPS 1e-5f

typedef __attribute__((ext_vector_type(8))) short short8;
typedef __attribute__((ext_vector_type(4))) float f32x4;

// ---------------------------------------------------------------------------
// Prep: f32 [n][C][HW] -> bf16 [n][HW][C].
// probT: XOR-swizzled within each 256B row (chunk bits 4-6 ^= hw&7) so the
// pair kernel can gl_lds linearly and ds_read conflict-spread (rule #21).
// galT: linear (read directly into registers).
// ---------------------------------------------------------------------------
__global__ void prep_kernel(const float* __restrict__ prob,
                            const float* __restrict__ gal,
                            unsigned short* __restrict__ probT,
                            unsigned short* __restrict__ galT) {
  int b = blockIdx.x;            // 512 blocks: 128 slices x 4 quarters
  int slice = b >> 2;
  int part = b & 3;
  const bool isProbe = (slice < 64);
  const float* src = isProbe ? prob + (size_t)slice * NC * HW
                             : gal + (size_t)(slice - 64) * NC * HW;
  unsigned short* dst = isProbe ? probT + (size_t)slice * HW * NC
                                : galT + (size_t)(slice - 64) * HW * NC;
  int begin = part * (NC * HW / 4);
  int end = begin + (NC * HW / 4);
  for (int idx = begin + threadIdx.x; idx < end; idx += blockDim.x) {
    int hw = idx >> 7;           // 0..191
    int c = idx & 127;
    unsigned short bits =
        __builtin_bit_cast(unsigned short, __float2bfloat16(src[c * HW + hw]));
    int col = isProbe ? ((((2 * c) ^ ((hw & 7) << 4))) >> 1) : c;
    dst[hw * NC + col] = bits;
  }
}

// ---------------------------------------------------------------------------
// Pair kernel: 512 blocks = g*8 + pc (8 probes each) -> exactly 2 blocks/CU.
// 4 waves; wave w: gal rows w*48..+47 persistent in regs (a[3][4]).
// Probe processed as two 96-col halves; 24KB LDS tiles double-buffered,
// staged async via global_load_lds (issued before MFMA, drained at barrier).
// ---------------------------------------------------------------------------
__device__ __forceinline__ void gl_lds16(const void* gsrc, void* ldst) {
  __builtin_amdgcn_global_load_lds(
      (const __attribute__((address_space(1))) void*)gsrc,
      (__attribute__((address_space(3))) void*)ldst, 16, 0, 0);
}

__global__ __launch_bounds__(256, 2)
void pair_kernel(const unsigned short* __restrict__ galT,
                 const unsigned short* __restrict__ probT,
                 const float* __restrict__ fc_w,
                 float* __restrict__ Wout,
                 float* __restrict__ sPart,
                 float* __restrict__ qPart) {
  __shared__ char ldsP[2][24576];     // double-buffered probe half-tile
  __shared__ float cmPart[4][96];     // per-wave col-max partials (this half)
  __shared__ float rmPart[192];       // final row-max per gal row (h==1)
  __shared__ float red[4];

  const int tid = threadIdx.x;
  const int lane = tid & 63;
  const int wid = tid >> 6;          // 0..3 : gal row group (48 rows)
  const int q = lane >> 4;           // 0..3
  const int r16 = lane & 15;
  const int swz = (r16 & 7) << 4;

  const int g = blockIdx.x >> 3;
  const int pc = blockIdx.x & 7;

  // persistent gallery A-frags: row = wid*48 + m*16 + r16, k-bytes ks*64+q*16
  const char* gbase = (const char*)(galT + (size_t)g * HW * NC);
  short8 a[3][4];
  #pragma unroll
  for (int m = 0; m < 3; ++m)
    #pragma unroll
    for (int ks = 0; ks < 4; ++ks)
      a[m][ks] = *(const short8*)(gbase + (wid * 48 + m * 16 + r16) * 256 + ks * 64 + q * 16);

  // fc weights for combiner threads
  const float wcm0 = (tid < 96) ? fc_w[tid] : 0.f;         // col feat s=tid (h0)
  const float wcm1 = (tid < 96) ? fc_w[96 + tid] : 0.f;    // h1
  const float wrmt = (tid < 192) ? fc_w[192 + tid] : 0.f;  // row feat r=tid

  const char* pTbase = (const char*)probT;

  // stage sub-tile 0
  {
    const char* src = pTbase + (size_t)(pc * 8) * 49152;
    #pragma unroll
    for (int c = 0; c < 6; ++c)
      gl_lds16(src + (wid * 6 + c) * 1024 + lane * 16, &ldsP[0][(wid * 6 + c) * 1024]);
  }
  __syncthreads();

  float s_acc = 0.f, q_acc = 0.f;
  float rm[3][4];
  float wp = 0.f;

  for (int t = 0; t < 16; ++t) {
    const int h = t & 1;
    const int p = pc * 8 + (t >> 1);
    const char* cur = ldsP[t & 1];

    if (t + 1 < 16) {  // async prefetch next half-tile
      const int tn = t + 1;
      const char* src = pTbase + (size_t)(pc * 8 + (tn >> 1)) * 49152 + (tn & 1) * 24576;
      char* dst = ldsP[tn & 1];
      #pragma unroll
      for (int c = 0; c < 6; ++c)
        gl_lds16(src + (wid * 6 + c) * 1024 + lane * 16, dst + (wid * 6 + c) * 1024);
    }
    if (h == 0) wp = 0.f;

    f32x4 acc[3][6];
    #pragma unroll
    for (int m = 0; m < 3; ++m)
      #pragma unroll
      for (int n = 0; n < 6; ++n) acc[m][n] = (f32x4){0.f, 0.f, 0.f, 0.f};

    #pragma unroll
    for (int n = 0; n < 6; ++n) {
      #pragma unroll
      for (int ks = 0; ks < 4; ++ks) {
        short8 bf = *(const short8*)(cur + (n * 16 + r16) * 256 + ((ks * 64 + q * 16) ^ swz));
        #pragma unroll
        for (int m = 0; m < 3; ++m)
          acc[m][n] = __builtin_amdgcn_mfma_f32_16x16x32_bf16(a[m][ks], bf, acc[m][n], 0, 0, 0);
      }
    }

    // col-max over this wave's 48 rows, per col s' = n*16+r16
    #pragma unroll
    for (int n = 0; n < 6; ++n) {
      float cm = fmaxf(fmaxf(acc[0][n][0], acc[0][n][1]),
                       fmaxf(acc[0][n][2], acc[0][n][3]));
      #pragma unroll
      for (int m = 1; m < 3; ++m)
        #pragma unroll
        for (int j = 0; j < 4; ++j) cm = fmaxf(cm, acc[m][n][j]);
      cm = fmaxf(cm, __shfl_xor(cm, 16));
      cm = fmaxf(cm, __shfl_xor(cm, 32));
      if (lane < 16) cmPart[wid][n * 16 + r16] = cm;
    }
    // row-max partial (over this half's 96 cols), carried in regs
    #pragma unroll
    for (int m = 0; m < 3; ++m) {
      #pragma unroll
      for (int j = 0; j < 4; ++j) {
        float v = acc[m][0][j];
        #pragma unroll
        for (int n = 1; n < 6; ++n) v = fmaxf(v, acc[m][n][j]);
        v = fmaxf(v, __shfl_xor(v, 1));
        v = fmaxf(v, __shfl_xor(v, 2));
        v = fmaxf(v, __shfl_xor(v, 4));
        v = fmaxf(v, __shfl_xor(v, 8));
        rm[m][j] = h ? fmaxf(rm[m][j], v) : v;
      }
    }
    if (h == 1) {  // publish final row-max: row = wid*48 + m*16 + q*4 + j
      #pragma unroll
      for (int m = 0; m < 3; ++m)
        #pragma unroll
        for (int j = 0; j < 4; ++j)
          if (r16 == j) rmPart[wid * 48 + m * 16 + q * 4 + j] = rm[m][j];
    }
    __syncthreads();   // A: cmPart/rmPart ready; all reads of `cur` done

    if (tid < 96) {
      float cmf = fmaxf(fmaxf(cmPart[0][tid], cmPart[1][tid]),
                        fmaxf(cmPart[2][tid], cmPart[3][tid]));
      s_acc += cmf; q_acc += cmf * cmf;
      wp += cmf * (h ? wcm1 : wcm0);
    }
    if (h == 1) {
      if (tid < 192) {
        float rv = rmPart[tid];
        s_acc += rv; q_acc += rv * rv;
        wp += rv * wrmt;
      }
      #pragma unroll
      for (int msk = 1; msk < 64; msk <<= 1) wp += __shfl_xor(wp, msk);
      if (lane == 0) red[wid] = wp;
    }
    __syncthreads();   // B: combine done; prefetch drained (vmcnt0 at barrier)
    if (h == 1 && tid == 0)
      Wout[p * 64 + g] = red[0] + red[1] + red[2] + red[3];
  }

  // block partials for BN stats
  #pragma unroll
  for (int msk = 1; msk < 64; msk <<= 1) {
    s_acc += __shfl_xor(s_acc, msk);
    q_acc += __shfl_xor(q_acc, msk);
  }
  __syncthreads();
  if (lane == 0) { cmPart[0][wid] = s_acc; cmPart[0][4 + wid] = q_acc; }
  __syncthreads();
  if (tid == 0) {
    sPart[blockIdx.x] = cmPart[0][0] + cmPart[0][1] + cmPart[0][2] + cmPart[0][3];
    qPart[blockIdx.x] = cmPart[0][4] + cmPart[0][5] + cmPart[0][6] + cmPart[0][7];
  }
}

// ---------------------------------------------------------------------------
// Finalize: exact BN -> fc -> BN chain. One block, 512 threads.
// ---------------------------------------------------------------------------
__device__ __forceinline__ float block_sum_512(float v, float* rbuf, float* bc) {
  int t = threadIdx.x, lane = t & 63, wid = t >> 6;
  #pragma unroll
  for (int m = 1; m < 64; m <<= 1) v += __shfl_xor(v, m);
  if (lane == 0) rbuf[wid] = v;
  __syncthreads();
  if (t == 0) {
    float r = 0.f;
    for (int i = 0; i < 8; ++i) r += rbuf[i];
    bc[0] = r;
  }
  __syncthreads();
  float res = bc[0];
  __syncthreads();
  return res;
}

__global__ void finalize_kernel(const float* __restrict__ Wv,
                                const float* __restrict__ sPart,
                                const float* __restrict__ qPart,
                                const float* __restrict__ fc_w,
                                const float* __restrict__ fc_b,
                                const float* __restrict__ bn_g,
                                const float* __restrict__ bn_b,
                                const float* __restrict__ lbn_g,
                                const float* __restrict__ lbn_b,
                                float* __restrict__ out) {
  __shared__ float rbuf[8];
  __shared__ float bc[1];
  const int t = threadIdx.x;  // 512

  float S = block_sum_512(sPart[t], rbuf, bc);
  float Q = block_sum_512(qPart[t], rbuf, bc);
  float SW = block_sum_512((t < 384) ? fc_w[t] : 0.f, rbuf, bc);

  const float Nf = 4096.0f * 384.0f;
  float mu = S / Nf;
  float var = Q / Nf - mu * mu;
  float istd = rsqrtf(var + KEPS);
  float cA = istd * bn_g[0];
  float off = bn_b[0] * SW + fc_b[0] - cA * mu * SW;

  float l[8];
  float ls = 0.f;
  #pragma unroll
  for (int i = 0; i < 8; ++i) {
    int n = t + i * 512;
    l[i] = cA * Wv[n] + off;
    ls += l[i];
  }
  float LS = block_sum_512(ls, rbuf, bc);
  float lmu = LS / 4096.0f;
  float lq = 0.f;
  #pragma unroll
  for (int i = 0; i < 8; ++i) { float d = l[i] - lmu; lq += d * d; }
  float LQ = block_sum_512(lq, rbuf, bc);
  float lvar = LQ / 4096.0f;
  float sc = lbn_g[0] * rsqrtf(lvar + KEPS);
  float lb = lbn_b[0];
  #pragma unroll
  for (int i = 0; i < 8; ++i) {
    int n = t + i * 512;
    out[n] = (l[i] - lmu) * sc + lb;
  }
}

// ---------------------------------------------------------------------------
extern "C" void kernel_launch(void* const* d_in, const int* in_sizes, int n_in,
                              void* d_out, int out_size, void* d_ws, size_t ws_size,
                              hipStream_t stream) {
  const float* prob  = (const float*)d_in[0];
  const float* gal   = (const float*)d_in[1];
  const float* bn_g  = (const float*)d_in[2];
  const float* bn_b  = (const float*)d_in[3];
  const float* fc_w  = (const float*)d_in[4];
  const float* fc_b  = (const float*)d_in[5];
  const float* lbn_g = (const float*)d_in[6];
  const float* lbn_b = (const float*)d_in[7];
  float* out = (float*)d_out;

  char* ws = (char*)d_ws;
  unsigned short* probT = (unsigned short*)(ws);            // 3,145,728 B
  unsigned short* galT  = (unsigned short*)(ws + 3145728);  // 3,145,728 B
  float* Wv    = (float*)(ws + 6291456);                    // 16384 B
  float* sPart = (float*)(ws + 6307840);                    // 2048 B
  float* qPart = (float*)(ws + 6309888);                    // 2048 B

  prep_kernel<<<512, 256, 0, stream>>>(prob, gal, probT, galT);
  pair_kernel<<<512, 256, 0, stream>>>(galT, probT, fc_w, Wv, sPart, qPart);
  finalize_kernel<<<1, 512, 0, stream>>>(Wv, sPart, qPart, fc_w, fc_b,
                                         bn_g, bn_b, lbn_g, lbn_b, out);
}

// Round 4
// 75.999 us; speedup vs baseline: 1.8063x; 1.0552x over previous
//
#include <hip/hip_runtime.h>
#include <hip/hip_bf16.h>
#include <stdint.h>

#define HW 192
#define NC 128
#define KEPS 1e-5f

typedef __attribute__((ext_vector_type(8))) short short8;
typedef __attribute__((ext_vector_type(4))) float f32x4;

// ---------------------------------------------------------------------------
// Prep: f32 [n][C][HW] -> bf16 [n][HW][C].
// probT XOR-swizzled within each 256B row (byte col = (2c)^((hw&7)<<4)) so the
// pair kernel stages linearly (gl_lds) and ds_reads conflict-spread.
// galT linear (read straight into registers).
// ---------------------------------------------------------------------------
__global__ void prep_kernel(const float* __restrict__ prob,
                            const float* __restrict__ gal,
                            unsigned short* __restrict__ probT,
                            unsigned short* __restrict__ galT) {
  int b = blockIdx.x;            // 512 blocks: 128 slices x 4 quarters
  int slice = b >> 2;
  int part = b & 3;
  const bool isProbe = (slice < 64);
  const float* src = isProbe ? prob + (size_t)slice * NC * HW
                             : gal + (size_t)(slice - 64) * NC * HW;
  unsigned short* dst = isProbe ? probT + (size_t)slice * HW * NC
                                : galT + (size_t)(slice - 64) * HW * NC;
  int begin = part * (NC * HW / 4);
  int end = begin + (NC * HW / 4);
  for (int idx = begin + threadIdx.x; idx < end; idx += blockDim.x) {
    int hw = idx >> 7;           // 0..191
    int c = idx & 127;
    unsigned short bits =
        __builtin_bit_cast(unsigned short, __float2bfloat16(src[c * HW + hw]));
    int col = isProbe ? ((((2 * c) ^ ((hw & 7) << 4))) >> 1) : c;
    dst[hw * NC + col] = bits;
  }
}

// ---------------------------------------------------------------------------
__device__ __forceinline__ void gl_lds16(const void* gsrc, void* ldst) {
  __builtin_amdgcn_global_load_lds(
      (const __attribute__((address_space(1))) void*)gsrc,
      (__attribute__((address_space(3))) void*)ldst, 16, 0, 0);
}

// DPP row_ror max within 16-lane rows (VALU pipe, not LDS)
template <int CTRL>
__device__ __forceinline__ float dpp_max(float x) {
  int xi = __builtin_bit_cast(int, x);
  int yi = __builtin_amdgcn_update_dpp(xi, xi, CTRL, 0xf, 0xf, false);
  return fmaxf(x, __builtin_bit_cast(float, yi));
}
__device__ __forceinline__ float ror16_max(float x) {
  x = dpp_max<0x121>(x);   // row_ror:1
  x = dpp_max<0x122>(x);   // row_ror:2
  x = dpp_max<0x124>(x);   // row_ror:4
  x = dpp_max<0x128>(x);   // row_ror:8
  return x;
}

// ---------------------------------------------------------------------------
// Pair kernel: 512 blocks = g*8 + pc (8 probes each) -> 2 blocks/CU; XCD=pc.
// Waves 2x2: wave (wr,wc) owns gal rows wr*96..+95 (A in 96 VGPRs) and probe
// cols wc*48..+47 of the current 96-col half-tile (12 b128 LDS reads/half).
// Probe halves double-buffered in LDS via async global_load_lds.
// ---------------------------------------------------------------------------
__global__ __launch_bounds__(256, 2)
void pair_kernel(const unsigned short* __restrict__ galT,
                 const unsigned short* __restrict__ probT,
                 const float* __restrict__ fc_w,
                 float* __restrict__ Wout,
                 float* __restrict__ sPart,
                 float* __restrict__ qPart) {
  __shared__ char ldsP[2][24576];     // double-buffered 96-col half-tile
  __shared__ float cmPart[2][96];     // [wr][col-in-half] col-max partials
  __shared__ float rmPart[2][192];    // [wc][gal row] row-max partials
  __shared__ float red[4];

  const int tid = threadIdx.x;
  const int lane = tid & 63;
  const int wid = tid >> 6;
  const int wr = wid >> 1;           // gal-row half (0/1)
  const int wc = wid & 1;            // probe-col quarter within half (0/1)
  const int q = lane >> 4;           // 0..3
  const int r16 = lane & 15;
  const int swz = (r16 & 7) << 4;

  const int g = blockIdx.x >> 3;
  const int pc = blockIdx.x & 7;

  // persistent gallery A-frags: row = wr*96 + m*16 + r16
  const char* gbase = (const char*)(galT + (size_t)g * HW * NC);
  short8 a[6][4];
  #pragma unroll
  for (int m = 0; m < 6; ++m)
    #pragma unroll
    for (int ks = 0; ks < 4; ++ks)
      a[m][ks] = *(const short8*)(gbase + (wr * 96 + m * 16 + r16) * 256 + ks * 64 + q * 16);

  // fc weights for combiner threads
  const float wcm0 = (tid < 96) ? fc_w[tid] : 0.f;        // col feat s=tid (h0)
  const float wcm1 = (tid < 96) ? fc_w[96 + tid] : 0.f;   // h1
  const float wrmt = (tid < 192) ? fc_w[192 + tid] : 0.f; // row feat r=tid

  const char* pTbase = (const char*)probT;

  // stage half-tile 0
  {
    const char* src = pTbase + (size_t)(pc * 8) * 49152;
    #pragma unroll
    for (int c = 0; c < 6; ++c)
      gl_lds16(src + (wid * 6 + c) * 1024 + lane * 16, &ldsP[0][(wid * 6 + c) * 1024]);
  }
  __syncthreads();

  float s_acc = 0.f, q_acc = 0.f;
  float rm[6][4];
  float wp = 0.f;
  const f32x4 zz = (f32x4){0.f, 0.f, 0.f, 0.f};

  for (int t = 0; t < 16; ++t) {
    const int h = t & 1;
    const int p = pc * 8 + (t >> 1);
    const char* cur = ldsP[t & 1];

    if (t + 1 < 16) {  // async prefetch next half-tile
      const int tn = t + 1;
      const char* src = pTbase + (size_t)(pc * 8 + (tn >> 1)) * 49152 + (tn & 1) * 24576;
      char* dst = ldsP[tn & 1];
      #pragma unroll
      for (int c = 0; c < 6; ++c)
        gl_lds16(src + (wid * 6 + c) * 1024 + lane * 16, dst + (wid * 6 + c) * 1024);
    }
    if (h == 0) wp = 0.f;

    f32x4 acc[6][3];
    #pragma unroll
    for (int n = 0; n < 3; ++n) {
      const char* rowB = cur + (wc * 48 + n * 16 + r16) * 256;
      {
        short8 bf = *(const short8*)(rowB + ((q * 16) ^ swz));
        #pragma unroll
        for (int m = 0; m < 6; ++m)
          acc[m][n] = __builtin_amdgcn_mfma_f32_16x16x32_bf16(a[m][0], bf, zz, 0, 0, 0);
      }
      #pragma unroll
      for (int ks = 1; ks < 4; ++ks) {
        short8 bf = *(const short8*)(rowB + ((ks * 64 + q * 16) ^ swz));
        #pragma unroll
        for (int m = 0; m < 6; ++m)
          acc[m][n] = __builtin_amdgcn_mfma_f32_16x16x32_bf16(a[m][ks], bf, acc[m][n], 0, 0, 0);
      }
    }

    // ---- col-max partial over this wave's 96 rows; cols = wc*48+n*16+r16 ----
    #pragma unroll
    for (int n = 0; n < 3; ++n) {
      float cm = fmaxf(fmaxf(acc[0][n][0], acc[0][n][1]),
                       fmaxf(acc[0][n][2], acc[0][n][3]));
      #pragma unroll
      for (int m = 1; m < 6; ++m) {
        float t0 = fmaxf(fmaxf(acc[m][n][0], acc[m][n][1]),
                         fmaxf(acc[m][n][2], acc[m][n][3]));
        cm = fmaxf(cm, t0);
      }
      cm = fmaxf(cm, __shfl_xor(cm, 16));
      cm = fmaxf(cm, __shfl_xor(cm, 32));
      if (lane < 16) cmPart[wr][wc * 48 + n * 16 + r16] = cm;
    }
    // ---- row-max lane partial (defer cross-lane to h==1) ----
    #pragma unroll
    for (int m = 0; m < 6; ++m)
      #pragma unroll
      for (int j = 0; j < 4; ++j) {
        float v = fmaxf(fmaxf(acc[m][0][j], acc[m][1][j]), acc[m][2][j]);
        rm[m][j] = h ? fmaxf(rm[m][j], v) : v;
      }
    if (h == 1) {   // finish row-max: DPP 16-lane reduce (VALU), publish
      #pragma unroll
      for (int m = 0; m < 6; ++m)
        #pragma unroll
        for (int j = 0; j < 4; ++j) {
          float v = ror16_max(rm[m][j]);
          if (r16 == j) rmPart[wc][wr * 96 + m * 16 + q * 4 + j] = v;
        }
    }
    __syncthreads();   // A: partials visible; reads of `cur` done

    if (tid < 96) {
      float cmf = fmaxf(cmPart[0][tid], cmPart[1][tid]);
      s_acc += cmf; q_acc += cmf * cmf;
      wp += cmf * (h ? wcm1 : wcm0);
    }
    if (h == 1) {
      if (tid < 192) {
        float rv = fmaxf(rmPart[0][tid], rmPart[1][tid]);
        s_acc += rv; q_acc += rv * rv;
        wp += rv * wrmt;
      }
      #pragma unroll
      for (int msk = 1; msk < 64; msk <<= 1) wp += __shfl_xor(wp, msk);
      if (lane == 0) red[wid] = wp;
    }
    __syncthreads();   // B: combine done; prefetch drained (vmcnt0 at barrier)
    if (h == 1 && tid == 0)
      Wout[p * 64 + g] = red[0] + red[1] + red[2] + red[3];
  }

  // block partials for BN stats
  #pragma unroll
  for (int msk = 1; msk < 64; msk <<= 1) {
    s_acc += __shfl_xor(s_acc, msk);
    q_acc += __shfl_xor(q_acc, msk);
  }
  __syncthreads();
  if (lane == 0) { cmPart[0][wid] = s_acc; cmPart[0][4 + wid] = q_acc; }
  __syncthreads();
  if (tid == 0) {
    sPart[blockIdx.x] = cmPart[0][0] + cmPart[0][1] + cmPart[0][2] + cmPart[0][3];
    qPart[blockIdx.x] = cmPart[0][4] + cmPart[0][5] + cmPart[0][6] + cmPart[0][7];
  }
}

// ---------------------------------------------------------------------------
// Finalize: exact BN -> fc -> BN chain. One block, 512 threads.
// ---------------------------------------------------------------------------
__device__ __forceinline__ float block_sum_512(float v, float* rbuf, float* bc) {
  int t = threadIdx.x, lane = t & 63, wid = t >> 6;
  #pragma unroll
  for (int m = 1; m < 64; m <<= 1) v += __shfl_xor(v, m);
  if (lane == 0) rbuf[wid] = v;
  __syncthreads();
  if (t == 0) {
    float r = 0.f;
    for (int i = 0; i < 8; ++i) r += rbuf[i];
    bc[0] = r;
  }
  __syncthreads();
  float res = bc[0];
  __syncthreads();
  return res;
}

__global__ void finalize_kernel(const float* __restrict__ Wv,
                                const float* __restrict__ sPart,
                                const float* __restrict__ qPart,
                                const float* __restrict__ fc_w,
                                const float* __restrict__ fc_b,
                                const float* __restrict__ bn_g,
                                const float* __restrict__ bn_b,
                                const float* __restrict__ lbn_g,
                                const float* __restrict__ lbn_b,
                                float* __restrict__ out) {
  __shared__ float rbuf[8];
  __shared__ float bc[1];
  const int t = threadIdx.x;  // 512

  float S = block_sum_512(sPart[t], rbuf, bc);
  float Q = block_sum_512(qPart[t], rbuf, bc);
  float SW = block_sum_512((t < 384) ? fc_w[t] : 0.f, rbuf, bc);

  const float Nf = 4096.0f * 384.0f;
  float mu = S / Nf;
  float var = Q / Nf - mu * mu;
  float istd = rsqrtf(var + KEPS);
  float cA = istd * bn_g[0];
  float off = bn_b[0] * SW + fc_b[0] - cA * mu * SW;

  float l[8];
  float ls = 0.f;
  #pragma unroll
  for (int i = 0; i < 8; ++i) {
    int n = t + i * 512;
    l[i] = cA * Wv[n] + off;
    ls += l[i];
  }
  float LS = block_sum_512(ls, rbuf, bc);
  float lmu = LS / 4096.0f;
  float lq = 0.f;
  #pragma unroll
  for (int i = 0; i < 8; ++i) { float d = l[i] - lmu; lq += d * d; }
  float LQ = block_sum_512(lq, rbuf, bc);
  float lvar = LQ / 4096.0f;
  float sc = lbn_g[0] * rsqrtf(lvar + KEPS);
  float lb = lbn_b[0];
  #pragma unroll
  for (int i = 0; i < 8; ++i) {
    int n = t + i * 512;
    out[n] = (l[i] - lmu) * sc + lb;
  }
}

// ---------------------------------------------------------------------------
extern "C" void kernel_launch(void* const* d_in, const int* in_sizes, int n_in,
                              void* d_out, int out_size, void* d_ws, size_t ws_size,
                              hipStream_t stream) {
  const float* prob  = (const float*)d_in[0];
  const float* gal   = (const float*)d_in[1];
  const float* bn_g  = (const float*)d_in[2];
  const float* bn_b  = (const float*)d_in[3];
  const float* fc_w  = (const float*)d_in[4];
  const float* fc_b  = (const float*)d_in[5];
  const float* lbn_g = (const float*)d_in[6];
  const float* lbn_b = (const float*)d_in[7];
  float* out = (float*)d_out;

  char* ws = (char*)d_ws;
  unsigned short* probT = (unsigned short*)(ws);            // 3,145,728 B
  unsigned short* galT  = (unsigned short*)(ws + 3145728);  // 3,145,728 B
  float* Wv    = (float*)(ws + 6291456);                    // 16384 B
  float* sPart = (float*)(ws + 6307840);                    // 2048 B
  float* qPart = (float*)(ws + 6309888);                    // 2048 B

  prep_kernel<<<512, 256, 0, stream>>>(prob, gal, probT, galT);
  pair_kernel<<<512, 256, 0, stream>>>(galT, probT, fc_w, Wv, sPart, qPart);
  finalize_kernel<<<1, 512, 0, stream>>>(Wv, sPart, qPart, fc_w, fc_b,
                                         bn_g, bn_b, lbn_g, lbn_b, out);
}